// Round 1
// baseline (319.335 us; speedup 1.0000x reference)
//
#include <hip/hip_runtime.h>

using f16   = _Float16;
using f16x8 = __attribute__((ext_vector_type(8))) _Float16;
using f32x4 = __attribute__((ext_vector_type(4))) float;
using u32x4 = __attribute__((ext_vector_type(4))) unsigned int;

#define MFMA16(a, b, c) __builtin_amdgcn_mfma_f32_16x16x32_f16((a), (b), (c), 0, 0, 0)

namespace {
constexpr int kT = 8, kWd = 14, kS = 196;
constexpr int kN = 1568;      // T*S (sequence length per batch)
constexpr int kM = 3136;      // B*N (GEMM rows)
constexpr int kHeads = 12;
constexpr int kNp = 1664;     // padded N (13*128)
// workspace byte offsets (all 256-aligned)
constexpr size_t OFF_Q  = 0;            // [24][Np][64] f16
constexpr size_t OFF_K  = 5111808;      // [24][Np][64] f16
constexpr size_t OFF_V  = 10223616;     // [24][64][Np] f16 (transposed)
constexpr size_t OFF_RH = 15335424;     // [24][Np][14] f32
constexpr size_t OFF_RW = 17571840;     // [24][Np][14] f32
constexpr size_t OFF_RT = 19808256;     // [24][Np][8]  f32
constexpr size_t OFF_O  = 21086208;     // [3200][768] f16
constexpr size_t WS_TOTAL = 26001408;
}

// ---------------- QKV GEMM: C[3136,2304] = X[3136,768] @ W[2304,768]^T ----------
// epilogue scatters into q[bh][n][d], k[bh][n][d], v^T[bh][d][n] (f16, padded)
__global__ __launch_bounds__(256) void arp_gemm_qkv(
    const float* __restrict__ X, const float* __restrict__ W,
    f16* __restrict__ qf, f16* __restrict__ kf, f16* __restrict__ vT) {
  __shared__ f16 sA[128 * 40];  // stride 40 (pad 8) -> 2-way-max LDS conflicts
  __shared__ f16 sB[128 * 40];
  const int tid = threadIdx.x, lane = tid & 63, wv = tid >> 6;
  const int m0 = blockIdx.y * 128, n0 = blockIdx.x * 128;
  const int wm = (wv & 1) * 64, wn = (wv >> 1) * 64;
  const int frow = lane & 15, fcol = (lane >> 4) * 8;
  const f32x4 vzero = {0.f, 0.f, 0.f, 0.f};
  f32x4 acc[4][4];
  for (int i = 0; i < 4; ++i)
    for (int j = 0; j < 4; ++j) acc[i][j] = vzero;

  for (int kt = 0; kt < 24; ++kt) {  // K=768, BK=32
    // stage A (fp32 -> f16): 128x32 tile, 1024 float4 chunks
#pragma unroll
    for (int i = 0; i < 4; ++i) {
      int idx = i * 256 + tid;
      int r = idx >> 3, c4 = (idx & 7) * 4;
      float4 v = {0.f, 0.f, 0.f, 0.f};
      int gm = m0 + r;
      if (gm < kM) v = *(const float4*)(X + (size_t)gm * 768 + kt * 32 + c4);
      f16* dst = &sA[r * 40 + c4];
      dst[0] = (f16)v.x; dst[1] = (f16)v.y; dst[2] = (f16)v.z; dst[3] = (f16)v.w;
    }
    // stage B (fp32 -> f16): rows n0..n0+127 of W (N=2304 exact, no guard)
#pragma unroll
    for (int i = 0; i < 4; ++i) {
      int idx = i * 256 + tid;
      int r = idx >> 3, c4 = (idx & 7) * 4;
      float4 v = *(const float4*)(W + (size_t)(n0 + r) * 768 + kt * 32 + c4);
      f16* dst = &sB[r * 40 + c4];
      dst[0] = (f16)v.x; dst[1] = (f16)v.y; dst[2] = (f16)v.z; dst[3] = (f16)v.w;
    }
    __syncthreads();
    f16x8 af[4], bf[4];
#pragma unroll
    for (int t = 0; t < 4; ++t) {
      af[t] = *(const f16x8*)&sA[(wm + t * 16 + frow) * 40 + fcol];
      bf[t] = *(const f16x8*)&sB[(wn + t * 16 + frow) * 40 + fcol];
    }
#pragma unroll
    for (int mt = 0; mt < 4; ++mt)
#pragma unroll
      for (int nt = 0; nt < 4; ++nt)
        acc[mt][nt] = MFMA16(af[mt], bf[nt], acc[mt][nt]);
    __syncthreads();
  }
  // epilogue: col = which*768 + head*64 + d
#pragma unroll
  for (int mt = 0; mt < 4; ++mt) {
    int rbase = m0 + wm + mt * 16 + (lane >> 4) * 4;
#pragma unroll
    for (int nt = 0; nt < 4; ++nt) {
      int col0 = n0 + wn + nt * 16;        // multiple of 16, uniform per nt
      int which = col0 / 768;
      int rem = col0 - which * 768;
      int hh = rem >> 6;
      int d = (rem & 63) + frow;
#pragma unroll
      for (int rg = 0; rg < 4; ++rg) {
        int m = rbase + rg;
        if (m < kM) {
          int b = (m >= kN) ? 1 : 0;
          int ns = m - b * kN;
          int bh = b * kHeads + hh;
          f16 hv = (f16)acc[mt][nt][rg];
          if (which == 0)      qf[((size_t)bh * kNp + ns) * 64 + d] = hv;
          else if (which == 1) kf[((size_t)bh * kNp + ns) * 64 + d] = hv;
          else                 vT[((size_t)bh * 64 + d) * kNp + ns] = hv;
        }
      }
    }
  }
}

// ---------------- rel-pos bias tables: relX[bh][q][k2] = q_vec . rel_pos[idx] ----
__global__ __launch_bounds__(256) void arp_rel_tables(
    const f16* __restrict__ qf,
    const float* __restrict__ Rh, const float* __restrict__ Rw, const float* __restrict__ Rt,
    float* __restrict__ relH, float* __restrict__ relW, float* __restrict__ relT) {
  int tid = blockIdx.x * 256 + threadIdx.x;
  const int TOT = 24 * kN * 36;
  if (tid >= TOT) return;
  int e = tid % 36;
  int rem = tid / 36;
  int q = rem % kN;
  int bh = rem / kN;
  int tq = q / kS, sr = q - tq * kS;
  int hq = sr / kWd, wq = sr - hq * kWd;
  const f16* qv = qf + ((size_t)bh * kNp + q) * 64;
  const float* R;
  float* out;
  if (e < 14)      { R = Rh + (hq - e + 13) * 64;        out = relH + ((size_t)bh * kNp + q) * 14 + e; }
  else if (e < 28) { int w2 = e - 14; R = Rw + (wq - w2 + 13) * 64; out = relW + ((size_t)bh * kNp + q) * 14 + w2; }
  else             { int t2 = e - 28; R = Rt + (tq - t2 + 7) * 64;  out = relT + ((size_t)bh * kNp + q) * 8 + t2; }
  float sum = 0.f;
#pragma unroll
  for (int c = 0; c < 64; ++c) sum += (float)qv[c] * R[c];
  *out = sum;
}

// ---------------- flash attention with decomposed bias --------------------------
// grid (25 q-tiles of 64, 24 bh); 4 waves x 16 q-rows; K-tiles of 128 over Np=1664
__global__ __launch_bounds__(256) void arp_attn(
    const f16* __restrict__ qf, const f16* __restrict__ kf, const f16* __restrict__ vT,
    const float* __restrict__ relH, const float* __restrict__ relW, const float* __restrict__ relT,
    f16* __restrict__ Of) {
  __shared__ f16 sK[128 * 72];        // [key][72] valid 64, pad 8
  __shared__ f16 sV[64 * 136];        // [d][136] valid 128, pad 8
  __shared__ f16 sP[4][16 * 136];     // per-wave P round-trip
  __shared__ float sRH[64 * 14], sRW[64 * 14], sRT[64 * 8];
  __shared__ unsigned char sT2[128], sH2[128], sW2[128];

  const int tid = threadIdx.x, lane = tid & 63, wv = tid >> 6;
  const int q0 = blockIdx.x * 64;
  const int bh = blockIdx.y;
  const int b = bh / kHeads, hh = bh - b * kHeads;
  const int frow = lane & 15, quad = lane >> 4;
  const f32x4 vzero = {0.f, 0.f, 0.f, 0.f};

  {  // load per-q-row bias tables (rows q0..q0+63, padded region is zeroed)
    const float* s1 = relH + ((size_t)bh * kNp + q0) * 14;
    for (int i = tid; i < 64 * 14; i += 256) sRH[i] = s1[i];
    const float* s2 = relW + ((size_t)bh * kNp + q0) * 14;
    for (int i = tid; i < 64 * 14; i += 256) sRW[i] = s2[i];
    const float* s3 = relT + ((size_t)bh * kNp + q0) * 8;
    for (int i = tid; i < 64 * 8; i += 256) sRT[i] = s3[i];
  }
  // persistent Q fragments (A-layout), rows q0 + wv*16 + frow
  f16x8 aQ[2];
  {
    int row = q0 + wv * 16 + frow;
    const f16* qp = qf + ((size_t)bh * kNp + row) * 64 + quad * 8;
    aQ[0] = *(const f16x8*)(qp);
    aQ[1] = *(const f16x8*)(qp + 32);
  }
  float m_i[4], l_i[4], alpha[4];
  f32x4 Oc[4];
#pragma unroll
  for (int r = 0; r < 4; ++r) { m_i[r] = -__builtin_inff(); l_i[r] = 0.f; }
#pragma unroll
  for (int t = 0; t < 4; ++t) Oc[t] = vzero;

  for (int kt = 0; kt < 13; ++kt) {
    __syncthreads();
    // stage K tile [128][64] -> sK
#pragma unroll
    for (int i = 0; i < 4; ++i) {
      int idx = i * 256 + tid;
      int r = idx >> 3, c8 = (idx & 7) * 8;
      u32x4 v = *(const u32x4*)(kf + ((size_t)bh * kNp + kt * 128 + r) * 64 + c8);
      *(u32x4*)&sK[r * 72 + c8] = v;
    }
    // stage V^T tile [64][128] -> sV
#pragma unroll
    for (int i = 0; i < 4; ++i) {
      int idx = i * 256 + tid;
      int r = idx >> 4, c8 = (idx & 15) * 8;
      u32x4 v = *(const u32x4*)(vT + ((size_t)bh * 64 + r) * kNp + kt * 128 + c8);
      *(u32x4*)&sV[r * 136 + c8] = v;
    }
    if (tid < 128) {  // j -> (t2,h2,w2) LUT for this k-tile
      int j = kt * 128 + tid;
      int t2 = j / kS;
      int rm = j - t2 * kS;
      int h2 = rm / kWd;
      sT2[tid] = (unsigned char)(t2 > 7 ? 7 : t2);
      sH2[tid] = (unsigned char)h2;
      sW2[tid] = (unsigned char)(rm - h2 * kWd);
    }
    __syncthreads();

    // QK^T: S[16 x 128] per wave
    f32x4 Sc[8];
#pragma unroll
    for (int nt = 0; nt < 8; ++nt) {
      f16x8 bK0 = *(const f16x8*)&sK[(nt * 16 + frow) * 72 + quad * 8];
      f16x8 bK1 = *(const f16x8*)&sK[(nt * 16 + frow) * 72 + 32 + quad * 8];
      Sc[nt] = MFMA16(aQ[0], bK0, vzero);
      Sc[nt] = MFMA16(aQ[1], bK1, Sc[nt]);
    }
    // bias + mask (scale only the QK part; bias uses unscaled q)
    const int rbl = wv * 16 + quad * 4;
    float pv[8][4];
#pragma unroll
    for (int nt = 0; nt < 8; ++nt) {
      int jc = nt * 16 + frow;
      int t2 = sT2[jc], h2 = sH2[jc], w2 = sW2[jc];
      bool valid = (kt * 128 + jc) < kN;
#pragma unroll
      for (int r = 0; r < 4; ++r) {
        float s = Sc[nt][r] * 0.125f
                + sRT[(rbl + r) * 8 + t2] + sRH[(rbl + r) * 14 + h2] + sRW[(rbl + r) * 14 + w2];
        pv[nt][r] = valid ? s : -1e30f;
      }
    }
    // online softmax per row (16-lane butterfly within row group)
#pragma unroll
    for (int r = 0; r < 4; ++r) {
      float mx = pv[0][r];
#pragma unroll
      for (int nt = 1; nt < 8; ++nt) mx = fmaxf(mx, pv[nt][r]);
#pragma unroll
      for (int off = 1; off < 16; off <<= 1) mx = fmaxf(mx, __shfl_xor(mx, off, 64));
      float mn = fmaxf(m_i[r], mx);
      alpha[r] = __expf(m_i[r] - mn);
      m_i[r] = mn;
      float rs = 0.f;
#pragma unroll
      for (int nt = 0; nt < 8; ++nt) {
        float p = __expf(pv[nt][r] - mn);
        pv[nt][r] = p;
        rs += p;
      }
#pragma unroll
      for (int off = 1; off < 16; off <<= 1) rs += __shfl_xor(rs, off, 64);
      l_i[r] = l_i[r] * alpha[r] + rs;
    }
#pragma unroll
    for (int t = 0; t < 4; ++t) {
      Oc[t][0] *= alpha[0]; Oc[t][1] *= alpha[1];
      Oc[t][2] *= alpha[2]; Oc[t][3] *= alpha[3];
    }
    // P: C-layout -> LDS -> A-layout (per-wave buffer, intra-wave dep only)
#pragma unroll
    for (int nt = 0; nt < 8; ++nt)
#pragma unroll
      for (int r = 0; r < 4; ++r)
        sP[wv][(quad * 4 + r) * 136 + nt * 16 + frow] = (f16)pv[nt][r];
    // PV: O[16 x 64] += P[16 x 128] @ V[128 x 64]
#pragma unroll
    for (int kc = 0; kc < 4; ++kc) {
      f16x8 aP = *(const f16x8*)&sP[wv][frow * 136 + kc * 32 + quad * 8];
#pragma unroll
      for (int t = 0; t < 4; ++t) {
        f16x8 bV = *(const f16x8*)&sV[(t * 16 + frow) * 136 + kc * 32 + quad * 8];
        Oc[t] = MFMA16(aP, bV, Oc[t]);
      }
    }
  }
  // epilogue: normalize and store O[b*N+row][hh*64 + d] as f16
#pragma unroll
  for (int t = 0; t < 4; ++t)
#pragma unroll
    for (int r = 0; r < 4; ++r) {
      int row = q0 + wv * 16 + quad * 4 + r;
      if (row < kN) {
        float val = Oc[t][r] / l_i[r];
        Of[((size_t)(b * kN + row)) * 768 + hh * 64 + t * 16 + frow] = (f16)val;
      }
    }
}

// ---------------- proj GEMM: out[3136,768] = O[3136,768] @ Wp[768,768]^T + bias --
__global__ __launch_bounds__(256) void arp_gemm_proj(
    const f16* __restrict__ A, const float* __restrict__ W,
    const float* __restrict__ bias, float* __restrict__ out) {
  __shared__ f16 sA[128 * 40];
  __shared__ f16 sB[128 * 40];
  const int tid = threadIdx.x, lane = tid & 63, wv = tid >> 6;
  const int m0 = blockIdx.y * 128, n0 = blockIdx.x * 128;
  const int wm = (wv & 1) * 64, wn = (wv >> 1) * 64;
  const int frow = lane & 15, fcol = (lane >> 4) * 8;
  const f32x4 vzero = {0.f, 0.f, 0.f, 0.f};
  f32x4 acc[4][4];
  for (int i = 0; i < 4; ++i)
    for (int j = 0; j < 4; ++j) acc[i][j] = vzero;

  for (int kt = 0; kt < 24; ++kt) {
    // stage A (already f16, rows padded to 3200 & zeroed): 512 chunks of 8
#pragma unroll
    for (int i = 0; i < 2; ++i) {
      int idx = i * 256 + tid;
      int r = idx >> 2, c8 = (idx & 3) * 8;
      u32x4 v = *(const u32x4*)(A + (size_t)(m0 + r) * 768 + kt * 32 + c8);
      *(u32x4*)&sA[r * 40 + c8] = v;
    }
    // stage B (fp32 -> f16)
#pragma unroll
    for (int i = 0; i < 4; ++i) {
      int idx = i * 256 + tid;
      int r = idx >> 3, c4 = (idx & 7) * 4;
      float4 v = *(const float4*)(W + (size_t)(n0 + r) * 768 + kt * 32 + c4);
      f16* dst = &sB[r * 40 + c4];
      dst[0] = (f16)v.x; dst[1] = (f16)v.y; dst[2] = (f16)v.z; dst[3] = (f16)v.w;
    }
    __syncthreads();
    f16x8 af[4], bf[4];
#pragma unroll
    for (int t = 0; t < 4; ++t) {
      af[t] = *(const f16x8*)&sA[(wm + t * 16 + frow) * 40 + fcol];
      bf[t] = *(const f16x8*)&sB[(wn + t * 16 + frow) * 40 + fcol];
    }
#pragma unroll
    for (int mt = 0; mt < 4; ++mt)
#pragma unroll
      for (int nt = 0; nt < 4; ++nt)
        acc[mt][nt] = MFMA16(af[mt], bf[nt], acc[mt][nt]);
    __syncthreads();
  }
#pragma unroll
  for (int mt = 0; mt < 4; ++mt) {
    int rbase = m0 + wm + mt * 16 + (lane >> 4) * 4;
#pragma unroll
    for (int nt = 0; nt < 4; ++nt) {
      int col = n0 + wn + nt * 16 + frow;
      float bv = bias[col];
#pragma unroll
      for (int rg = 0; rg < 4; ++rg) {
        int m = rbase + rg;
        if (m < kM) out[(size_t)m * 768 + col] = acc[mt][nt][rg] + bv;
      }
    }
  }
}

extern "C" void kernel_launch(void* const* d_in, const int* in_sizes, int n_in,
                              void* d_out, int out_size, void* d_ws, size_t ws_size,
                              hipStream_t stream) {
  if (ws_size < WS_TOTAL) return;  // fail loud via wrong output
  const float* x      = (const float*)d_in[0];
  const float* qkv_w  = (const float*)d_in[1];
  const float* proj_w = (const float*)d_in[2];
  const float* proj_b = (const float*)d_in[3];
  const float* rph    = (const float*)d_in[4];
  const float* rpw    = (const float*)d_in[5];
  const float* rpt    = (const float*)d_in[6];
  char* ws = (char*)d_ws;
  f16*   qf   = (f16*)(ws + OFF_Q);
  f16*   kf   = (f16*)(ws + OFF_K);
  f16*   vT   = (f16*)(ws + OFF_V);
  float* relH = (float*)(ws + OFF_RH);
  float* relW = (float*)(ws + OFF_RW);
  float* relT = (float*)(ws + OFF_RT);
  f16*   Of   = (f16*)(ws + OFF_O);

  // zero workspace (padded rows/cols must read as 0; harness poisons ws with 0xAA)
  hipMemsetAsync(d_ws, 0, WS_TOTAL, stream);

  arp_gemm_qkv<<<dim3(18, 25), 256, 0, stream>>>(x, qkv_w, qf, kf, vT);

  int relTot = 24 * kN * 36;
  arp_rel_tables<<<(relTot + 255) / 256, 256, 0, stream>>>(qf, rph, rpw, rpt, relH, relW, relT);

  arp_attn<<<dim3(25, 24), 256, 0, stream>>>(qf, kf, vT, relH, relW, relT, Of);

  arp_gemm_proj<<<dim3(6, 25), 256, 0, stream>>>(Of, proj_w, proj_b, (float*)d_out);
}